// Round 1
// baseline (27044.919 us; speedup 1.0000x reference)
//
#include <hip/hip_runtime.h>

#define H 64
#define G4 256  // 4*H

__device__ __forceinline__ float sigmoid_f(float x) {
  return 1.f / (1.f + __expf(-x));
}
// tanh via exp; saturates correctly at +/-1 for large |x|
__device__ __forceinline__ float tanh_f(float x) {
  float e = __expf(2.f * x);
  return 1.f - 2.f / (e + 1.f);
}

// xw[t][j] = x[t][0]*W[0][j] + x[t][1]*W[1][j] + b[j]
__global__ __launch_bounds__(G4) void proj_x(const float* __restrict__ x,
                                             const float* __restrict__ W,
                                             const float* __restrict__ b,
                                             float* __restrict__ xw) {
  const int t = blockIdx.x;
  const int j = threadIdx.x;
  const float x0 = x[2 * t];
  const float x1 = x[2 * t + 1];
  xw[(size_t)t * G4 + j] = fmaf(x0, W[j], fmaf(x1, W[G4 + j], b[j]));
}

// xw[t][j] = b[j] + sum_k hseq[t][k] * W[k][j]   (W is [64,256] row-major)
__global__ __launch_bounds__(G4) void proj_h(const float* __restrict__ hseq,
                                             const float* __restrict__ W,
                                             const float* __restrict__ b,
                                             float* __restrict__ xw) {
  __shared__ float sh[H];
  const int t = blockIdx.x;
  const int j = threadIdx.x;
  if (j < H) sh[j] = hseq[(size_t)t * H + j];
  __syncthreads();
  float acc = b[j];
#pragma unroll
  for (int k = 0; k < H; ++k) acc = fmaf(sh[k], W[k * G4 + j], acc);
  xw[(size_t)t * G4 + j] = acc;
}

// Sequential LSTM scan over T steps. One workgroup, 256 threads.
// Thread j owns gate-output column j: z[j] = xw[t][j] + sum_k h[k]*U[k][j].
// Gate order i,f,g,o in blocks of 64. hseq gets h[t] every step.
__global__ __launch_bounds__(G4) void lstm_scan(const float* __restrict__ xw,
                                                const float* __restrict__ U,
                                                float* __restrict__ hseq,
                                                int T) {
  __shared__ float sh_h[H];
  __shared__ float sh_a[G4];
  const int j = threadIdx.x;

  // U column into registers (64 VGPRs), coalesced loads
  float u[H];
#pragma unroll
  for (int k = 0; k < H; ++k) u[k] = U[k * G4 + j];

  float c = 0.f;
  if (j < H) sh_h[j] = 0.f;
  __syncthreads();

  float nxt = xw[j];  // prefetched xw[t][j]
  for (int t = 0; t < T; ++t) {
    float a0 = nxt, a1 = 0.f, a2 = 0.f, a3 = 0.f;
    // prefetch next step's xw (hidden under this step's compute)
    const int tn = (t + 1 < T) ? (t + 1) : (T - 1);
    nxt = xw[(size_t)tn * G4 + j];

    const float4* h4 = (const float4*)sh_h;
#pragma unroll
    for (int kk = 0; kk < H / 4; ++kk) {
      float4 hv = h4[kk];
      a0 = fmaf(hv.x, u[4 * kk + 0], a0);
      a1 = fmaf(hv.y, u[4 * kk + 1], a1);
      a2 = fmaf(hv.z, u[4 * kk + 2], a2);
      a3 = fmaf(hv.w, u[4 * kk + 3], a3);
    }
    const float acc = (a0 + a1) + (a2 + a3);

    // gate activation, wave-uniform branch: waves 0,1,3 sigmoid; wave 2 tanh
    float a;
    if (j < 2 * H || j >= 3 * H) a = sigmoid_f(acc);
    else a = tanh_f(acc);
    sh_a[j] = a;
    __syncthreads();

    if (j < H) {
      const float gi = sh_a[j];
      const float gf = sh_a[j + H];
      const float gg = sh_a[j + 2 * H];
      const float go = sh_a[j + 3 * H];
      c = fmaf(gf, c, gi * gg);
      const float h = go * tanh_f(c);
      sh_h[j] = h;
      hseq[(size_t)t * H + j] = h;
    }
    __syncthreads();
  }
}

// Dense head: relu(h3@Wd1+bd1) -> relu(@Wd2+bd2) -> @Wl+bl
__global__ __launch_bounds__(64) void head_k(const float* __restrict__ hlast,
                                             const float* __restrict__ Wd1,
                                             const float* __restrict__ bd1,
                                             const float* __restrict__ Wd2,
                                             const float* __restrict__ bd2,
                                             const float* __restrict__ Wl,
                                             const float* __restrict__ bl,
                                             float* __restrict__ out) {
  __shared__ float s_h[H];
  __shared__ float s_a[20];
  __shared__ float s_b[20];
  const int j = threadIdx.x;
  s_h[j] = hlast[j];
  __syncthreads();
  if (j < 20) {
    float acc = bd1[j];
#pragma unroll
    for (int k = 0; k < H; ++k) acc = fmaf(s_h[k], Wd1[k * 20 + j], acc);
    s_a[j] = fmaxf(acc, 0.f);
  }
  __syncthreads();
  if (j < 20) {
    float acc = bd2[j];
#pragma unroll
    for (int k = 0; k < 20; ++k) acc = fmaf(s_a[k], Wd2[k * 20 + j], acc);
    s_b[j] = fmaxf(acc, 0.f);
  }
  __syncthreads();
  if (j < 10) {
    float acc = bl[j];
#pragma unroll
    for (int k = 0; k < 20; ++k) acc = fmaf(s_b[k], Wl[k * 10 + j], acc);
    out[j] = acc;
  }
}

extern "C" void kernel_launch(void* const* d_in, const int* in_sizes, int n_in,
                              void* d_out, int out_size, void* d_ws, size_t ws_size,
                              hipStream_t stream) {
  const float* x   = (const float*)d_in[0];
  const float* W1  = (const float*)d_in[1];
  const float* U1  = (const float*)d_in[2];
  const float* b1  = (const float*)d_in[3];
  const float* W2  = (const float*)d_in[4];
  const float* U2  = (const float*)d_in[5];
  const float* b2  = (const float*)d_in[6];
  const float* W3  = (const float*)d_in[7];
  const float* U3  = (const float*)d_in[8];
  const float* b3  = (const float*)d_in[9];
  const float* Wd1 = (const float*)d_in[10];
  const float* bd1 = (const float*)d_in[11];
  const float* Wd2 = (const float*)d_in[12];
  const float* bd2 = (const float*)d_in[13];
  const float* Wl  = (const float*)d_in[14];
  const float* bl  = (const float*)d_in[15];
  const int T = in_sizes[0] / 2;  // 16384

  // workspace layout: xw [T,256] | hA [T,64] | hB [T,64]  = 24 MB total
  float* xw = (float*)d_ws;
  float* hA = xw + (size_t)T * G4;
  float* hB = hA + (size_t)T * H;

  // Layer 1
  proj_x<<<T, G4, 0, stream>>>(x, W1, b1, xw);
  lstm_scan<<<1, G4, 0, stream>>>(xw, U1, hA, T);
  // Layer 2
  proj_h<<<T, G4, 0, stream>>>(hA, W2, b2, xw);
  lstm_scan<<<1, G4, 0, stream>>>(xw, U2, hB, T);
  // Layer 3
  proj_h<<<T, G4, 0, stream>>>(hB, W3, b3, xw);
  lstm_scan<<<1, G4, 0, stream>>>(xw, U3, hA, T);
  // Head on last hidden state
  head_k<<<1, 64, 0, stream>>>(hA + (size_t)(T - 1) * H, Wd1, bd1, Wd2, bd2,
                               Wl, bl, (float*)d_out);
}

// Round 2
// 21501.381 us; speedup vs baseline: 1.2578x; 1.2578x over previous
//
#include <hip/hip_runtime.h>

#define H 64
#define G4 256  // 4*H
#define CH 16   // scan chunk (steps of xw prefetched per thread)
#define TB 64   // timesteps per block in proj_h

typedef float v2f __attribute__((ext_vector_type(2)));

__device__ __forceinline__ float sigmoid_f(float x) {
  return 1.f / (1.f + __expf(-x));
}
__device__ __forceinline__ float tanh_f(float x) {
  float e = __expf(2.f * x);
  return 1.f - 2.f / (e + 1.f);
}

// Workgroup barrier that drains ONLY lgkmcnt (LDS), not vmcnt.
// Our cross-thread dependencies are LDS-only; global loads/stores may stay
// in flight across the barrier (compiler still inserts vmcnt waits at uses).
// "memory" clobber = compiler fence so LDS ops can't be moved across it.
__device__ __forceinline__ void wg_barrier() {
  asm volatile("s_waitcnt lgkmcnt(0)\n\ts_barrier" ::: "memory");
}

// xw[t][j] = x[t][0]*W[0][j] + x[t][1]*W[1][j] + b[j]
__global__ __launch_bounds__(G4) void proj_x(const float* __restrict__ x,
                                             const float* __restrict__ W,
                                             const float* __restrict__ b,
                                             float* __restrict__ xw) {
  const int t = blockIdx.x;
  const int j = threadIdx.x;
  const float x0 = x[2 * t];
  const float x1 = x[2 * t + 1];
  xw[(size_t)t * G4 + j] = fmaf(x0, W[j], fmaf(x1, W[G4 + j], b[j]));
}

// xw[t][j] = b[j] + sum_k hseq[t][k] * W[k][j]; W kept in registers per
// thread (column j), TB timesteps of h staged in LDS per block.
__global__ __launch_bounds__(G4) void proj_h(const float* __restrict__ hseq,
                                             const float* __restrict__ W,
                                             const float* __restrict__ b,
                                             float* __restrict__ xw) {
  __shared__ float sh[TB * H];
  const int j = threadIdx.x;
  const int t0 = blockIdx.x * TB;

  float w[H];
#pragma unroll
  for (int k = 0; k < H; ++k) w[k] = W[k * G4 + j];
  const float bj = b[j];

  // stage TB*H = 4096 consecutive floats, vectorized
  const float4* src = (const float4*)(hseq + (size_t)t0 * H);
  float4* dst = (float4*)sh;
#pragma unroll
  for (int r = 0; r < (TB * H / 4) / G4; ++r) dst[r * G4 + j] = src[r * G4 + j];
  __syncthreads();

  for (int tt = 0; tt < TB; ++tt) {
    const float4* h4 = (const float4*)(sh + tt * H);
    float a0 = bj, a1 = 0.f, a2 = 0.f, a3 = 0.f;
#pragma unroll
    for (int kk = 0; kk < H / 4; ++kk) {
      float4 hv = h4[kk];
      a0 = fmaf(hv.x, w[4 * kk + 0], a0);
      a1 = fmaf(hv.y, w[4 * kk + 1], a1);
      a2 = fmaf(hv.z, w[4 * kk + 2], a2);
      a3 = fmaf(hv.w, w[4 * kk + 3], a3);
    }
    xw[(size_t)(t0 + tt) * G4 + j] = (a0 + a1) + (a2 + a3);
  }
}

// Sequential LSTM scan. 1 workgroup x 256 threads (4 waves, 1 per SIMD).
// Thread j owns gate column j. No global op is waited on inside a step:
// xw comes from a double-buffered register chunk; h stores fire-and-forget.
__global__ __launch_bounds__(G4) void lstm_scan(const float* __restrict__ xw,
                                                const float* __restrict__ U,
                                                float* __restrict__ hseq,
                                                int T) {
  __shared__ float sh_h[H];
  __shared__ float sh_a[G4];
  const int j = threadIdx.x;

  // U column j, paired along k for packed fma
  v2f u2[H / 2];
#pragma unroll
  for (int k = 0; k < H / 2; ++k) {
    u2[k][0] = U[(2 * k) * G4 + j];
    u2[k][1] = U[(2 * k + 1) * G4 + j];
  }

  float c = 0.f;
  if (j < H) sh_h[j] = 0.f;
  wg_barrier();

  const bool is_sig = (j < 2 * H) || (j >= 3 * H);  // wave-uniform

  float xwb[CH], xwn[CH];
#pragma unroll
  for (int q = 0; q < CH; ++q) xwn[q] = xw[(size_t)q * G4 + j];

  for (int t0 = 0; t0 < T; t0 += CH) {
#pragma unroll
    for (int q = 0; q < CH; ++q) xwb[q] = xwn[q];
    // prefetch next chunk (clamped); in flight across the whole chunk
    const int tn = (t0 + CH < T) ? (t0 + CH) : t0;
#pragma unroll
    for (int q = 0; q < CH; ++q) xwn[q] = xw[(size_t)(tn + q) * G4 + j];

#pragma unroll
    for (int q = 0; q < CH; ++q) {
      v2f acc2 = {xwb[q], 0.f};
      v2f acc2b = {0.f, 0.f};
      const float4* h4 = (const float4*)sh_h;
#pragma unroll
      for (int kk = 0; kk < H / 4; ++kk) {
        float4 hv = h4[kk];
        v2f hlo = {hv.x, hv.y};
        v2f hhi = {hv.z, hv.w};
        acc2 = __builtin_elementwise_fma(hlo, u2[2 * kk], acc2);
        acc2b = __builtin_elementwise_fma(hhi, u2[2 * kk + 1], acc2b);
      }
      v2f s = acc2 + acc2b;
      const float acc = s[0] + s[1];

      sh_a[j] = is_sig ? sigmoid_f(acc) : tanh_f(acc);
      wg_barrier();

      if (j < H) {
        const float gi = sh_a[j];
        const float gf = sh_a[j + H];
        const float gg = sh_a[j + 2 * H];
        const float go = sh_a[j + 3 * H];
        c = fmaf(gf, c, gi * gg);
        const float h = go * tanh_f(c);
        sh_h[j] = h;
        hseq[(size_t)(t0 + q) * H + j] = h;  // fire-and-forget store
      }
      wg_barrier();
    }
  }
}

// Dense head: relu(h3@Wd1+bd1) -> relu(@Wd2+bd2) -> @Wl+bl
__global__ __launch_bounds__(64) void head_k(const float* __restrict__ hlast,
                                             const float* __restrict__ Wd1,
                                             const float* __restrict__ bd1,
                                             const float* __restrict__ Wd2,
                                             const float* __restrict__ bd2,
                                             const float* __restrict__ Wl,
                                             const float* __restrict__ bl,
                                             float* __restrict__ out) {
  __shared__ float s_h[H];
  __shared__ float s_a[20];
  __shared__ float s_b[20];
  const int j = threadIdx.x;
  s_h[j] = hlast[j];
  __syncthreads();
  if (j < 20) {
    float acc = bd1[j];
#pragma unroll
    for (int k = 0; k < H; ++k) acc = fmaf(s_h[k], Wd1[k * 20 + j], acc);
    s_a[j] = fmaxf(acc, 0.f);
  }
  __syncthreads();
  if (j < 20) {
    float acc = bd2[j];
#pragma unroll
    for (int k = 0; k < 20; ++k) acc = fmaf(s_a[k], Wd2[k * 20 + j], acc);
    s_b[j] = fmaxf(acc, 0.f);
  }
  __syncthreads();
  if (j < 10) {
    float acc = bl[j];
#pragma unroll
    for (int k = 0; k < 20; ++k) acc = fmaf(s_b[k], Wl[k * 10 + j], acc);
    out[j] = acc;
  }
}

extern "C" void kernel_launch(void* const* d_in, const int* in_sizes, int n_in,
                              void* d_out, int out_size, void* d_ws, size_t ws_size,
                              hipStream_t stream) {
  const float* x   = (const float*)d_in[0];
  const float* W1  = (const float*)d_in[1];
  const float* U1  = (const float*)d_in[2];
  const float* b1  = (const float*)d_in[3];
  const float* W2  = (const float*)d_in[4];
  const float* U2  = (const float*)d_in[5];
  const float* b2  = (const float*)d_in[6];
  const float* W3  = (const float*)d_in[7];
  const float* U3  = (const float*)d_in[8];
  const float* b3  = (const float*)d_in[9];
  const float* Wd1 = (const float*)d_in[10];
  const float* bd1 = (const float*)d_in[11];
  const float* Wd2 = (const float*)d_in[12];
  const float* bd2 = (const float*)d_in[13];
  const float* Wl  = (const float*)d_in[14];
  const float* bl  = (const float*)d_in[15];
  const int T = in_sizes[0] / 2;  // 16384

  // workspace layout: xw [T,256] | hA [T,64] | hB [T,64]  = 24 MB total
  float* xw = (float*)d_ws;
  float* hA = xw + (size_t)T * G4;
  float* hB = hA + (size_t)T * H;

  // Layer 1
  proj_x<<<T, G4, 0, stream>>>(x, W1, b1, xw);
  lstm_scan<<<1, G4, 0, stream>>>(xw, U1, hA, T);
  // Layer 2
  proj_h<<<T / TB, G4, 0, stream>>>(hA, W2, b2, xw);
  lstm_scan<<<1, G4, 0, stream>>>(xw, U2, hB, T);
  // Layer 3
  proj_h<<<T / TB, G4, 0, stream>>>(hB, W3, b3, xw);
  lstm_scan<<<1, G4, 0, stream>>>(xw, U3, hA, T);
  // Head on last hidden state
  head_k<<<1, 64, 0, stream>>>(hA + (size_t)(T - 1) * H, Wd1, bd1, Wd2, bd2,
                               Wl, bl, (float*)d_out);
}